// Round 2
// baseline (2242.345 us; speedup 1.0000x reference)
//
#include <hip/hip_runtime.h>
#include <hip/hip_bf16.h>

typedef float f4 __attribute__((ext_vector_type(4)));

#define BN_EPS   1e-5f
#define PCEN_EPS 1e-6f

// workspace layout (floats)
#define P1_ELEMS (2048*15*29*29)   // pool1: [B][15][29][29]
#define P2_ELEMS (2048*30*11*11)   // pool2 flat: [B][3630]
#define FC1P_HALF (2048*200)       // fc1 partial per k-split

// ---------------------------------------------------------------------------
// K1: PCEN (EMA over w per (b,h) row) + conv1 7x7 (1->15) + BN + ReLU + 2x2 pool
// block = 1 image (2048 blocks x 256 threads)
// ---------------------------------------------------------------------------
__global__ __launch_bounds__(256) void k_pcen_conv1(
    const float* __restrict__ x,
    const float* __restrict__ log_s, const float* __restrict__ log_alpha,
    const float* __restrict__ log_delta, const float* __restrict__ log_r,
    const float* __restrict__ w1, const float* __restrict__ cb1,
    const float* __restrict__ g1, const float* __restrict__ be1,
    const float* __restrict__ mu1, const float* __restrict__ va1,
    float* __restrict__ pool1)
{
    __shared__ float bufA[64*65];   // stride 65: scan banks (h+w)%32 -> 2-way (free)
    __shared__ float bufB[64*72];   // stride 72: 16B-aligned rows for b128 conv reads
    const int tid = threadIdx.x;
    const int b = blockIdx.x;

    // ---- load image (coalesced float4) ----
    const f4* xin = (const f4*)(x + (size_t)b * 4096);
    for (int i = tid; i < 1024; i += 256) {
        f4 v = xin[i];
        int flat = i * 4, h = flat >> 6, w = flat & 63;
        float* p = &bufA[h*65 + w];
        p[0] = v[0]; p[1] = v[1]; p[2] = v[2]; p[3] = v[3];
    }
    __syncthreads();

    // ---- PCEN scan along w (one lane per h row) ----
    if (tid < 64) {
        const float s     = expf(log_s[0]);
        const float alpha = expf(log_alpha[0]);
        const float delta = expf(log_delta[0]);
        const float r     = expf(log_r[0]);
        const float dr    = expf(r * logf(delta));
        float* row = &bufA[tid*65];
        float m = 0.f;
        for (int w = 0; w < 64; ++w) {
            float xv = row[w];
            m = (w == 0) ? s * xv : (1.f - s) * m + s * xv;
            float t = xv * expf(-alpha * logf(m + PCEN_EPS)) + delta;
            row[w] = expf(r * logf(t)) - dr;
        }
    }
    __syncthreads();

    // ---- re-layout to stride-72 buffer, zero-pad cols 64..71 ----
    for (int i = tid; i < 64*72; i += 256) {
        int h = i / 72, w = i - h*72;
        bufB[i] = (w < 64) ? bufA[h*65 + w] : 0.f;
    }
    __syncthreads();

    // ---- conv + bn + relu + pool ----
    // tiles: 15c x 29py x 8xt ; tile = 2 conv rows x 8 conv cols (4 pooled px)
    #pragma unroll 1
    for (int t = tid; t < 3480; t += 256) {
        int c   = t / 232;
        int rem = t - c*232;
        int py  = rem >> 3, xt = rem & 7;
        int x0  = xt * 8, y0 = py * 2;
        const float* wp = w1 + c*49;

        float acc0[8] = {0,0,0,0,0,0,0,0};
        float acc1[8] = {0,0,0,0,0,0,0,0};
        #pragma unroll
        for (int ky = 0; ky < 8; ++ky) {
            const float* rp = &bufB[(y0 + ky)*72 + x0];
            float in[16] __attribute__((aligned(16)));
            *(f4*)&in[0]  = *(const f4*)&rp[0];
            *(f4*)&in[4]  = *(const f4*)&rp[4];
            *(f4*)&in[8]  = *(const f4*)&rp[8];
            *(f4*)&in[12] = *(const f4*)&rp[12];
            if (ky < 7) {
                #pragma unroll
                for (int kx = 0; kx < 7; ++kx) {
                    float wv = wp[ky*7 + kx];
                    #pragma unroll
                    for (int cx = 0; cx < 8; ++cx) acc0[cx] += in[cx+kx] * wv;
                }
            }
            if (ky > 0) {
                #pragma unroll
                for (int kx = 0; kx < 7; ++kx) {
                    float wv = wp[(ky-1)*7 + kx];
                    #pragma unroll
                    for (int cx = 0; cx < 8; ++cx) acc1[cx] += in[cx+kx] * wv;
                }
            }
        }

        float A  = g1[c] * rsqrtf(va1[c] + BN_EPS);
        float Bb = (cb1[c] - mu1[c]) * A + be1[c];
        float* outp = pool1 + (((size_t)b*15 + c)*29 + py)*29;
        #pragma unroll
        for (int j = 0; j < 4; ++j) {
            int px = xt*4 + j;
            if (px < 29) {
                float v00 = acc0[2*j]*A + Bb, v01 = acc0[2*j+1]*A + Bb;
                float v10 = acc1[2*j]*A + Bb, v11 = acc1[2*j+1]*A + Bb;
                float p = fmaxf(fmaxf(v00, v01), fmaxf(v10, v11));
                outp[px] = fmaxf(p, 0.f);
            }
        }
    }
}

// ---------------------------------------------------------------------------
// K2: conv2 7x7 (15->30) + BN + ReLU + 2x2 pool (23->11, only 22x22 computed)
// block = 1 image; tile = 2 out-channels x 2 conv rows x 4 conv cols
// ---------------------------------------------------------------------------
__global__ __launch_bounds__(256) void k_conv2(
    const float* __restrict__ pool1, const float* __restrict__ w2,
    const float* __restrict__ cb2, const float* __restrict__ g2,
    const float* __restrict__ be2, const float* __restrict__ mu2,
    const float* __restrict__ va2, float* __restrict__ pool2)
{
    __shared__ float img[15*29*32];   // [ci][y][x], stride 32, cols 29..31 zero
    const int tid = threadIdx.x;
    const int b = blockIdx.x;

    const float* src = pool1 + (size_t)b * 12615;
    for (int i = tid; i < 13920; i += 256) {
        int c = i / 928;
        int rem = i - c*928;
        int y = rem >> 5, xx = rem & 31;
        img[i] = (xx < 29) ? src[c*841 + y*29 + xx] : 0.f;
    }
    __syncthreads();

    // tiles: 15 co-pairs x 11 py x 6 xt = 990
    #pragma unroll 1
    for (int t = tid; t < 990; t += 256) {
        int g   = t / 66;
        int rem = t - g*66;
        int py  = rem / 6;
        int xt  = rem - py*6;
        int x0  = xt * 4, y0 = py * 2;
        int co0 = g * 2;
        const float* wa = w2 + (size_t)(co0*15)*49;
        const float* wb = wa + 15*49;

        float acc[2][2][4] = {{{0,0,0,0},{0,0,0,0}},{{0,0,0,0},{0,0,0,0}}};
        #pragma unroll 1
        for (int ci = 0; ci < 15; ++ci) {
            const float* wpa = wa + ci*49;
            const float* wpb = wb + ci*49;
            #pragma unroll
            for (int ky = 0; ky < 8; ++ky) {
                const float* rp = &img[(ci*29 + y0 + ky)*32 + x0];
                float in[12] __attribute__((aligned(16)));
                *(f4*)&in[0] = *(const f4*)&rp[0];
                *(f4*)&in[4] = *(const f4*)&rp[4];
                *(f4*)&in[8] = *(const f4*)&rp[8];
                if (ky < 7) {
                    #pragma unroll
                    for (int kx = 0; kx < 7; ++kx) {
                        float u0 = wpa[ky*7 + kx], u1 = wpb[ky*7 + kx];
                        #pragma unroll
                        for (int cx = 0; cx < 4; ++cx) {
                            acc[0][0][cx] += in[cx+kx] * u0;
                            acc[1][0][cx] += in[cx+kx] * u1;
                        }
                    }
                }
                if (ky > 0) {
                    #pragma unroll
                    for (int kx = 0; kx < 7; ++kx) {
                        float u0 = wpa[(ky-1)*7 + kx], u1 = wpb[(ky-1)*7 + kx];
                        #pragma unroll
                        for (int cx = 0; cx < 4; ++cx) {
                            acc[0][1][cx] += in[cx+kx] * u0;
                            acc[1][1][cx] += in[cx+kx] * u1;
                        }
                    }
                }
            }
        }

        #pragma unroll
        for (int q = 0; q < 2; ++q) {
            int co = co0 + q;
            float A  = g2[co] * rsqrtf(va2[co] + BN_EPS);
            float Bb = (cb2[co] - mu2[co]) * A + be2[co];
            float* outp = pool2 + (size_t)b*3630 + co*121 + py*11;
            #pragma unroll
            for (int j = 0; j < 2; ++j) {
                int px = xt*2 + j;
                if (px < 11) {
                    float v00 = acc[q][0][2*j]*A + Bb, v01 = acc[q][0][2*j+1]*A + Bb;
                    float v10 = acc[q][1][2*j]*A + Bb, v11 = acc[q][1][2*j+1]*A + Bb;
                    outp[px] = fmaxf(fmaxf(fmaxf(v00, v01), fmaxf(v10, v11)), 0.f);
                }
            }
        }
    }
}

// ---------------------------------------------------------------------------
// K3a: fc1 GEMM partials.  C[2048,200] = A[2048,3630] * W^T, K split in 2.
// grid 256 = 32 Mtiles x 4 Ntiles(64) x 2 Ksplit; block 256 = 16x16, micro 4x4
// ---------------------------------------------------------------------------
__global__ __launch_bounds__(256) void k_fc1(
    const float* __restrict__ A, const float* __restrict__ W,
    float* __restrict__ part)
{
    __shared__ float As[64*68];  // transposed: [k][m]
    __shared__ float Bs[64*68];  // transposed: [k][n]
    const int tid = threadIdx.x;
    int bid = blockIdx.x;
    int ks = bid & 1;
    int nt = (bid >> 1) & 3;
    int mt = bid >> 3;
    int b0 = mt * 64, n0 = nt * 64;
    int kbeg = ks * 1815, kend = kbeg + 1815;
    int ty = tid >> 4, tx = tid & 15;

    float acc[4][4] = {{0,0,0,0},{0,0,0,0},{0,0,0,0},{0,0,0,0}};
    for (int kt = kbeg; kt < kend; kt += 64) {
        for (int i = tid; i < 4096; i += 256) {
            int k = i & 63, m = i >> 6;
            int gk = kt + k;
            As[k*68 + m] = (gk < kend) ? A[(size_t)(b0 + m)*3630 + gk] : 0.f;
            int n = n0 + m;
            Bs[k*68 + m] = (gk < kend && n < 200) ? W[(size_t)n*3630 + gk] : 0.f;
        }
        __syncthreads();
        #pragma unroll 8
        for (int kk = 0; kk < 64; ++kk) {
            f4 av = *(const f4*)&As[kk*68 + ty*4];
            f4 bv = *(const f4*)&Bs[kk*68 + tx*4];
            #pragma unroll
            for (int i = 0; i < 4; ++i)
                #pragma unroll
                for (int j = 0; j < 4; ++j)
                    acc[i][j] += av[i] * bv[j];
        }
        __syncthreads();
    }

    float* dst = part + (size_t)ks * FC1P_HALF;
    #pragma unroll
    for (int i = 0; i < 4; ++i) {
        int m = b0 + ty*4 + i;
        #pragma unroll
        for (int j = 0; j < 4; ++j) {
            int n = n0 + tx*4 + j;
            if (n < 200) dst[(size_t)m*200 + n] = acc[i][j];
        }
    }
}

// ---------------------------------------------------------------------------
// K3b: sum k-split partials + bias + ReLU, fc2 (200->2) + bias + sigmoid
// output is FLOAT32 (reference output dtype). one wave per batch row.
// ---------------------------------------------------------------------------
__global__ __launch_bounds__(256) void k_fc2(
    const float* __restrict__ part, const float* __restrict__ fb1,
    const float* __restrict__ W2, const float* __restrict__ fb2,
    float* __restrict__ out)
{
    int b = blockIdx.x * 4 + (threadIdx.x >> 6);
    int l = threadIdx.x & 63;
    const float* p0 = part + (size_t)b * 200;
    const float* p1 = p0 + FC1P_HALF;
    float a0 = 0.f, a1 = 0.f;
    #pragma unroll
    for (int j = 0; j < 4; ++j) {
        int n = l + j*64;
        if (n < 200) {
            float v = p0[n] + p1[n] + fb1[n];
            v = fmaxf(v, 0.f);
            a0 += v * W2[n];
            a1 += v * W2[200 + n];
        }
    }
    #pragma unroll
    for (int m = 32; m >= 1; m >>= 1) {
        a0 += __shfl_xor(a0, m);
        a1 += __shfl_xor(a1, m);
    }
    if (l == 0) {
        float z0 = a0 + fb2[0], z1 = a1 + fb2[1];
        out[b*2 + 0] = 1.f / (1.f + expf(-z0));
        out[b*2 + 1] = 1.f / (1.f + expf(-z1));
    }
}

// ---------------------------------------------------------------------------
extern "C" void kernel_launch(void* const* d_in, const int* in_sizes, int n_in,
                              void* d_out, int out_size, void* d_ws, size_t ws_size,
                              hipStream_t stream)
{
    const float* x         = (const float*)d_in[0];
    const float* log_s     = (const float*)d_in[1];
    const float* log_alpha = (const float*)d_in[2];
    const float* log_delta = (const float*)d_in[3];
    const float* log_r     = (const float*)d_in[4];
    const float* conv1_w   = (const float*)d_in[5];
    const float* conv1_b   = (const float*)d_in[6];
    const float* bn1_g     = (const float*)d_in[7];
    const float* bn1_b     = (const float*)d_in[8];
    const float* bn1_m     = (const float*)d_in[9];
    const float* bn1_v     = (const float*)d_in[10];
    const float* conv2_w   = (const float*)d_in[11];
    const float* conv2_b   = (const float*)d_in[12];
    const float* bn2_g     = (const float*)d_in[13];
    const float* bn2_b     = (const float*)d_in[14];
    const float* bn2_m     = (const float*)d_in[15];
    const float* bn2_v     = (const float*)d_in[16];
    const float* fc1_w     = (const float*)d_in[17];
    const float* fc1_b     = (const float*)d_in[18];
    const float* fc2_w     = (const float*)d_in[19];
    const float* fc2_b     = (const float*)d_in[20];

    float* ws    = (float*)d_ws;
    float* pool1 = ws;
    float* pool2 = ws + P1_ELEMS;
    float* part  = pool2 + P2_ELEMS;

    k_pcen_conv1<<<2048, 256, 0, stream>>>(x, log_s, log_alpha, log_delta, log_r,
                                           conv1_w, conv1_b, bn1_g, bn1_b, bn1_m, bn1_v,
                                           pool1);
    k_conv2<<<2048, 256, 0, stream>>>(pool1, conv2_w, conv2_b, bn2_g, bn2_b, bn2_m, bn2_v,
                                      pool2);
    k_fc1<<<256, 256, 0, stream>>>(pool2, fc1_w, part);
    k_fc2<<<512, 256, 0, stream>>>(part, fc1_b, fc2_w, fc2_b, (float*)d_out);
}

// Round 3
// 576.842 us; speedup vs baseline: 3.8873x; 3.8873x over previous
//
#include <hip/hip_runtime.h>
#include <hip/hip_bf16.h>

typedef float f4 __attribute__((ext_vector_type(4)));
typedef float f32x4 __attribute__((ext_vector_type(4)));
typedef short s8v __attribute__((ext_vector_type(8)));

#define BN_EPS   1e-5f
#define PCEN_EPS 1e-6f

// ---- workspace byte layout ----
#define POOL1_BYTES (2048UL*25088)                 // bf16 [b][h2][y28][x28][c8] = 25088 B/img
#define WBF_OFF     POOL1_BYTES
#define WBF_BYTES   (50UL*2*32*8*2)                // 51200 B
#define POOL2_OFF   (WBF_OFF + WBF_BYTES)          // float [b][3630]
#define POOL2_ELEMS (2048UL*3630)
#define PART_OFF    (POOL2_OFF + POOL2_ELEMS*4UL)
#define FC1P_HALF   (2048*200)

// ---------------------------------------------------------------------------
// K1: PCEN + conv1 7x7 (1->15) + BN + ReLU + 2x2 pool -> bf16 [b][h][y][x][c8]
// block = 1 image (2048 x 256). Only pooled region 28x28 is stored.
// ---------------------------------------------------------------------------
__global__ __launch_bounds__(256) void k_pcen_conv1(
    const float* __restrict__ x,
    const float* __restrict__ log_s, const float* __restrict__ log_alpha,
    const float* __restrict__ log_delta, const float* __restrict__ log_r,
    const float* __restrict__ w1, const float* __restrict__ cb1,
    const float* __restrict__ g1, const float* __restrict__ be1,
    const float* __restrict__ mu1, const float* __restrict__ va1,
    __hip_bfloat16* __restrict__ pool1)
{
    __shared__ float bufA[64*65];
    __shared__ float bufB[64*72];
    const int tid = threadIdx.x;
    const int b = blockIdx.x;

    const f4* xin = (const f4*)(x + (size_t)b * 4096);
    for (int i = tid; i < 1024; i += 256) {
        f4 v = xin[i];
        int flat = i * 4, h = flat >> 6, w = flat & 63;
        float* p = &bufA[h*65 + w];
        p[0] = v[0]; p[1] = v[1]; p[2] = v[2]; p[3] = v[3];
    }
    __syncthreads();

    if (tid < 64) {
        const float s     = expf(log_s[0]);
        const float alpha = expf(log_alpha[0]);
        const float delta = expf(log_delta[0]);
        const float r     = expf(log_r[0]);
        const float dr    = expf(r * logf(delta));
        float* row = &bufA[tid*65];
        float m = 0.f;
        for (int w = 0; w < 64; ++w) {
            float xv = row[w];
            m = (w == 0) ? s * xv : (1.f - s) * m + s * xv;
            float t = xv * expf(-alpha * logf(m + PCEN_EPS)) + delta;
            row[w] = expf(r * logf(t)) - dr;
        }
    }
    __syncthreads();

    for (int i = tid; i < 64*72; i += 256) {
        int h = i / 72, w = i - h*72;
        bufB[i] = (w < 64) ? bufA[h*65 + w] : 0.f;
    }
    __syncthreads();

    __hip_bfloat16* outb = pool1 + (size_t)b * 12544;  // 2*784*8 elems

    // zero-fill the ci=15 pad plane (h=1, c8=7); disjoint from value stores
    for (int p = tid; p < 784; p += 256)
        outb[(784 + p)*8 + 7] = __float2bfloat16(0.f);

    // tiles: 15c x 28py x 7xt ; tile = 2 conv rows x 8 conv cols (4 pooled px)
    #pragma unroll 1
    for (int t = tid; t < 2940; t += 256) {
        int c   = t / 196;
        int rem = t - c*196;
        int py  = rem / 7, xt = rem - (rem/7)*7;
        int x0  = xt * 8, y0 = py * 2;
        const float* wp = w1 + c*49;

        float acc0[8] = {0,0,0,0,0,0,0,0};
        float acc1[8] = {0,0,0,0,0,0,0,0};
        #pragma unroll
        for (int ky = 0; ky < 8; ++ky) {
            const float* rp = &bufB[(y0 + ky)*72 + x0];
            float in[16] __attribute__((aligned(16)));
            *(f4*)&in[0]  = *(const f4*)&rp[0];
            *(f4*)&in[4]  = *(const f4*)&rp[4];
            *(f4*)&in[8]  = *(const f4*)&rp[8];
            *(f4*)&in[12] = *(const f4*)&rp[12];
            if (ky < 7) {
                #pragma unroll
                for (int kx = 0; kx < 7; ++kx) {
                    float wv = wp[ky*7 + kx];
                    #pragma unroll
                    for (int cx = 0; cx < 8; ++cx) acc0[cx] += in[cx+kx] * wv;
                }
            }
            if (ky > 0) {
                #pragma unroll
                for (int kx = 0; kx < 7; ++kx) {
                    float wv = wp[(ky-1)*7 + kx];
                    #pragma unroll
                    for (int cx = 0; cx < 8; ++cx) acc1[cx] += in[cx+kx] * wv;
                }
            }
        }

        float A  = g1[c] * rsqrtf(va1[c] + BN_EPS);
        float Bb = (cb1[c] - mu1[c]) * A + be1[c];
        int h = c >> 3, c8 = c & 7;
        __hip_bfloat16* po = outb + ((size_t)h*784 + py*28)*8 + c8;
        #pragma unroll
        for (int j = 0; j < 4; ++j) {
            int px = xt*4 + j;     // 0..27, always valid
            float v00 = acc0[2*j]*A + Bb, v01 = acc0[2*j+1]*A + Bb;
            float v10 = acc1[2*j]*A + Bb, v11 = acc1[2*j+1]*A + Bb;
            float p = fmaxf(fmaxf(fmaxf(v00, v01), fmaxf(v10, v11)), 0.f);
            po[px*8] = __float2bfloat16(p);
        }
    }
}

// ---------------------------------------------------------------------------
// K_wprep: conv2 weights fp32 [30][15][7][7] -> bf16 [tap50][h2][co32][c8]
// tap = ky*7+kx; tap49 / ci15 / co>=30 are zero (K padding).
// ---------------------------------------------------------------------------
__global__ __launch_bounds__(256) void k_wprep(
    const float* __restrict__ w2, __hip_bfloat16* __restrict__ wbf)
{
    int i = blockIdx.x*256 + threadIdx.x;
    if (i >= 25600) return;
    int c8 = i & 7, co = (i >> 3) & 31, h = (i >> 8) & 1, tap = i >> 9;
    int ci = h*8 + c8;
    float v = 0.f;
    if (tap < 49 && ci < 15 && co < 30)
        v = w2[((co*15 + ci)*7 + tap/7)*7 + (tap%7)];
    wbf[i] = __float2bfloat16(v);
}

// ---------------------------------------------------------------------------
// K2: conv2 as implicit GEMM via mfma_f32_16x16x32_bf16 + fused BN/ReLU/pool.
// block = 1 image, 512 threads (8 waves). M = 484 conv px (pool-quad-major),
// N = 30 co, K = 25 steps x (2 taps x 16 ci). Wave tile: 4 Mfrag x 2 Nfrag.
// ---------------------------------------------------------------------------
__global__ __launch_bounds__(512, 4) void k_conv2(
    const ushort* __restrict__ pool1u, const ushort* __restrict__ wbfu,
    const float* __restrict__ cb2, const float* __restrict__ g2,
    const float* __restrict__ be2, const float* __restrict__ mu2,
    const float* __restrict__ va2, float* __restrict__ pool2)
{
    __shared__ ushort img_s[12544];   // [h2][p784][c8]  25088 B
    __shared__ ushort bs_s[25600];    // [tap50][h2][co32][c8]  51200 B

    const int tid = threadIdx.x;
    const int b = blockIdx.x;

    // stage image (linear 16B copy)
    {
        const f4* src = (const f4*)(pool1u + (size_t)b * 12544);
        f4* dst = (f4*)img_s;
        for (int i = tid; i < 1568; i += 512) dst[i] = src[i];
        const f4* wsrc = (const f4*)wbfu;
        f4* wdst = (f4*)bs_s;
        for (int i = tid; i < 3200; i += 512) wdst[i] = wsrc[i];
    }
    __syncthreads();

    const int l  = tid & 63;
    const int wv = tid >> 6;          // 0..7
    const int n16 = l & 15;
    const int Q4  = l >> 4;           // 0..3
    const int h   = Q4 & 1;           // ci half
    const int qh  = Q4 >> 1;          // tap-within-pair

    // per-lane A base addresses (bytes into img_s)
    int Abase[4];
    #pragma unroll
    for (int mf = 0; mf < 4; ++mf) {
        int P  = wv*64 + mf*16 + n16;
        int Pc = P < 483 ? P : 483;
        int pr = Pc >> 2, sb = Pc & 3;
        int py = pr / 11, px = pr - py*11;
        int oy = 2*py + (sb >> 1), ox = 2*px + (sb & 1);
        Abase[mf] = (h*784 + oy*28 + ox) * 16;
    }
    const int Bb0 = qh*1024 + h*512 + n16*16;
    const int Bb1 = Bb0 + 256;

    const char* imgc = (const char*)img_s;
    const char* bsc  = (const char*)bs_s;

    f32x4 acc[4][2];
    #pragma unroll
    for (int mf = 0; mf < 4; ++mf)
        #pragma unroll
        for (int nf = 0; nf < 2; ++nf)
            acc[mf][nf] = (f32x4){0.f, 0.f, 0.f, 0.f};

    #pragma unroll
    for (int t = 0; t < 25; ++t) {
        const int tap0 = 2*t;
        const int tap1 = (2*t + 1 <= 48) ? 2*t + 1 : 48;   // t=24: B[tap49]=0
        const int o0 = ((tap0/7)*28 + tap0%7) * 16;
        const int o1 = ((tap1/7)*28 + tap1%7) * 16;
        const int offA = qh ? o1 : o0;

        s8v a[4], bf[2];
        #pragma unroll
        for (int mf = 0; mf < 4; ++mf)
            a[mf] = *(const s8v*)(imgc + (Abase[mf] + offA));
        bf[0] = *(const s8v*)(bsc + (Bb0 + t*2048));
        bf[1] = *(const s8v*)(bsc + (Bb1 + t*2048));

        #pragma unroll
        for (int mf = 0; mf < 4; ++mf)
            #pragma unroll
            for (int nf = 0; nf < 2; ++nf)
                acc[mf][nf] = __builtin_amdgcn_mfma_f32_16x16x32_bf16(
                    a[mf], bf[nf], acc[mf][nf], 0, 0, 0);
    }

    // epilogue: BN + 2x2 pool (acc quad = pool window) + ReLU
    #pragma unroll
    for (int nf = 0; nf < 2; ++nf) {
        int co = nf*16 + n16;
        if (co >= 30) continue;
        float A  = g2[co] * rsqrtf(va2[co] + BN_EPS);
        float Bb = (cb2[co] - mu2[co]) * A + be2[co];
        float* outp = pool2 + (size_t)b*3630 + co*121;
        #pragma unroll
        for (int mf = 0; mf < 4; ++mf) {
            int pair = wv*16 + mf*4 + Q4;
            if (pair < 121) {
                f32x4 v = acc[mf][nf];
                float m01 = fmaxf(v[0]*A + Bb, v[1]*A + Bb);
                float m23 = fmaxf(v[2]*A + Bb, v[3]*A + Bb);
                outp[pair] = fmaxf(fmaxf(m01, m23), 0.f);
            }
        }
    }
}

// ---------------------------------------------------------------------------
// K3a: fc1 GEMM partials.  C[2048,200] = A[2048,3630] * W^T, K split in 2.
// ---------------------------------------------------------------------------
__global__ __launch_bounds__(256) void k_fc1(
    const float* __restrict__ A, const float* __restrict__ W,
    float* __restrict__ part)
{
    __shared__ float As[64*68];
    __shared__ float Bs[64*68];
    const int tid = threadIdx.x;
    int bid = blockIdx.x;
    int ks = bid & 1;
    int nt = (bid >> 1) & 3;
    int mt = bid >> 3;
    int b0 = mt * 64, n0 = nt * 64;
    int kbeg = ks * 1815, kend = kbeg + 1815;
    int ty = tid >> 4, tx = tid & 15;

    float acc[4][4] = {{0,0,0,0},{0,0,0,0},{0,0,0,0},{0,0,0,0}};
    for (int kt = kbeg; kt < kend; kt += 64) {
        for (int i = tid; i < 4096; i += 256) {
            int k = i & 63, m = i >> 6;
            int gk = kt + k;
            As[k*68 + m] = (gk < kend) ? A[(size_t)(b0 + m)*3630 + gk] : 0.f;
            int n = n0 + m;
            Bs[k*68 + m] = (gk < kend && n < 200) ? W[(size_t)n*3630 + gk] : 0.f;
        }
        __syncthreads();
        #pragma unroll 8
        for (int kk = 0; kk < 64; ++kk) {
            f4 av = *(const f4*)&As[kk*68 + ty*4];
            f4 bv = *(const f4*)&Bs[kk*68 + tx*4];
            #pragma unroll
            for (int i = 0; i < 4; ++i)
                #pragma unroll
                for (int j = 0; j < 4; ++j)
                    acc[i][j] += av[i] * bv[j];
        }
        __syncthreads();
    }

    float* dst = part + (size_t)ks * FC1P_HALF;
    #pragma unroll
    for (int i = 0; i < 4; ++i) {
        int m = b0 + ty*4 + i;
        #pragma unroll
        for (int j = 0; j < 4; ++j) {
            int n = n0 + tx*4 + j;
            if (n < 200) dst[(size_t)m*200 + n] = acc[i][j];
        }
    }
}

// ---------------------------------------------------------------------------
// K3b: sum partials + bias + ReLU, fc2 + bias + sigmoid -> float32
// ---------------------------------------------------------------------------
__global__ __launch_bounds__(256) void k_fc2(
    const float* __restrict__ part, const float* __restrict__ fb1,
    const float* __restrict__ W2, const float* __restrict__ fb2,
    float* __restrict__ out)
{
    int b = blockIdx.x * 4 + (threadIdx.x >> 6);
    int l = threadIdx.x & 63;
    const float* p0 = part + (size_t)b * 200;
    const float* p1 = p0 + FC1P_HALF;
    float a0 = 0.f, a1 = 0.f;
    #pragma unroll
    for (int j = 0; j < 4; ++j) {
        int n = l + j*64;
        if (n < 200) {
            float v = p0[n] + p1[n] + fb1[n];
            v = fmaxf(v, 0.f);
            a0 += v * W2[n];
            a1 += v * W2[200 + n];
        }
    }
    #pragma unroll
    for (int m = 32; m >= 1; m >>= 1) {
        a0 += __shfl_xor(a0, m);
        a1 += __shfl_xor(a1, m);
    }
    if (l == 0) {
        float z0 = a0 + fb2[0], z1 = a1 + fb2[1];
        out[b*2 + 0] = 1.f / (1.f + expf(-z0));
        out[b*2 + 1] = 1.f / (1.f + expf(-z1));
    }
}

// ---------------------------------------------------------------------------
extern "C" void kernel_launch(void* const* d_in, const int* in_sizes, int n_in,
                              void* d_out, int out_size, void* d_ws, size_t ws_size,
                              hipStream_t stream)
{
    const float* x         = (const float*)d_in[0];
    const float* log_s     = (const float*)d_in[1];
    const float* log_alpha = (const float*)d_in[2];
    const float* log_delta = (const float*)d_in[3];
    const float* log_r     = (const float*)d_in[4];
    const float* conv1_w   = (const float*)d_in[5];
    const float* conv1_b   = (const float*)d_in[6];
    const float* bn1_g     = (const float*)d_in[7];
    const float* bn1_b     = (const float*)d_in[8];
    const float* bn1_m     = (const float*)d_in[9];
    const float* bn1_v     = (const float*)d_in[10];
    const float* conv2_w   = (const float*)d_in[11];
    const float* conv2_b   = (const float*)d_in[12];
    const float* bn2_g     = (const float*)d_in[13];
    const float* bn2_b     = (const float*)d_in[14];
    const float* bn2_m     = (const float*)d_in[15];
    const float* bn2_v     = (const float*)d_in[16];
    const float* fc1_w     = (const float*)d_in[17];
    const float* fc1_b     = (const float*)d_in[18];
    const float* fc2_w     = (const float*)d_in[19];
    const float* fc2_b     = (const float*)d_in[20];

    char* wsb = (char*)d_ws;
    __hip_bfloat16* pool1 = (__hip_bfloat16*)wsb;
    __hip_bfloat16* wbf   = (__hip_bfloat16*)(wsb + WBF_OFF);
    float* pool2          = (float*)(wsb + POOL2_OFF);
    float* part           = (float*)(wsb + PART_OFF);

    k_wprep<<<100, 256, 0, stream>>>(conv2_w, wbf);
    k_pcen_conv1<<<2048, 256, 0, stream>>>(x, log_s, log_alpha, log_delta, log_r,
                                           conv1_w, conv1_b, bn1_g, bn1_b, bn1_m, bn1_v,
                                           pool1);
    k_conv2<<<2048, 512, 0, stream>>>((const ushort*)pool1, (const ushort*)wbf,
                                      conv2_b, bn2_g, bn2_b, bn2_m, bn2_v, pool2);
    k_fc1<<<256, 256, 0, stream>>>(pool2, fc1_w, part);
    k_fc2<<<512, 256, 0, stream>>>(part, fc1_b, fc2_w, fc2_b, (float*)d_out);
}

// Round 4
// 343.003 us; speedup vs baseline: 6.5374x; 1.6817x over previous
//
#include <hip/hip_runtime.h>
#include <hip/hip_bf16.h>

typedef float f4 __attribute__((ext_vector_type(4)));
typedef float f32x4 __attribute__((ext_vector_type(4)));
typedef short s8v __attribute__((ext_vector_type(8)));

#define BN_EPS   1e-5f
#define PCEN_EPS 1e-6f

// ---- workspace byte layout (all offsets 16B-aligned) ----
#define POOL1_OFF   0UL
#define POOL1_BYTES (2048UL*25088)                 // bf16 [b][h2][y28][x28][c8]
#define WBF_OFF     (POOL1_OFF + POOL1_BYTES)
#define WBF_BYTES   (50UL*2*32*8*2)                // conv2 W bf16: 51200 B
#define WFC1_OFF    (WBF_OFF + WBF_BYTES)
#define WFC1_BYTES  (208UL*3840*2)                 // fc1 W bf16 padded
#define POOL2_OFF   (WFC1_OFF + WFC1_BYTES)
#define POOL2_BYTES (2048UL*3840*2)                // bf16 [b][3840] (K-padded)
#define PART_OFF    (POOL2_OFF + POOL2_BYTES)
#define PART_BYTES  (8UL*2048*208*4)               // fp32 [ks8][b][208]

// ---------------------------------------------------------------------------
// K1: PCEN + conv1 7x7 (1->15) + BN + ReLU + 2x2 pool -> bf16 [b][h][y][x][c8]
// ---------------------------------------------------------------------------
__global__ __launch_bounds__(256) void k_pcen_conv1(
    const float* __restrict__ x,
    const float* __restrict__ log_s, const float* __restrict__ log_alpha,
    const float* __restrict__ log_delta, const float* __restrict__ log_r,
    const float* __restrict__ w1, const float* __restrict__ cb1,
    const float* __restrict__ g1, const float* __restrict__ be1,
    const float* __restrict__ mu1, const float* __restrict__ va1,
    __hip_bfloat16* __restrict__ pool1)
{
    __shared__ float bufA[64*65];
    __shared__ float bufB[64*72];
    const int tid = threadIdx.x;
    const int b = blockIdx.x;

    const f4* xin = (const f4*)(x + (size_t)b * 4096);
    for (int i = tid; i < 1024; i += 256) {
        f4 v = xin[i];
        int flat = i * 4, h = flat >> 6, w = flat & 63;
        float* p = &bufA[h*65 + w];
        p[0] = v[0]; p[1] = v[1]; p[2] = v[2]; p[3] = v[3];
    }
    __syncthreads();

    if (tid < 64) {
        const float s     = expf(log_s[0]);
        const float alpha = expf(log_alpha[0]);
        const float delta = expf(log_delta[0]);
        const float r     = expf(log_r[0]);
        const float dr    = expf(r * logf(delta));
        float* row = &bufA[tid*65];
        float m = 0.f;
        for (int w = 0; w < 64; ++w) {
            float xv = row[w];
            m = (w == 0) ? s * xv : (1.f - s) * m + s * xv;
            float t = xv * expf(-alpha * logf(m + PCEN_EPS)) + delta;
            row[w] = expf(r * logf(t)) - dr;
        }
    }
    __syncthreads();

    for (int i = tid; i < 64*72; i += 256) {
        int h = i / 72, w = i - h*72;
        bufB[i] = (w < 64) ? bufA[h*65 + w] : 0.f;
    }
    __syncthreads();

    __hip_bfloat16* outb = pool1 + (size_t)b * 12544;

    // zero-fill the ci=15 pad plane (h=1, c8=7)
    for (int p = tid; p < 784; p += 256)
        outb[(784 + p)*8 + 7] = __float2bfloat16(0.f);

    #pragma unroll 1
    for (int t = tid; t < 2940; t += 256) {
        int c   = t / 196;
        int rem = t - c*196;
        int py  = rem / 7, xt = rem - (rem/7)*7;
        int x0  = xt * 8, y0 = py * 2;
        const float* wp = w1 + c*49;

        float acc0[8] = {0,0,0,0,0,0,0,0};
        float acc1[8] = {0,0,0,0,0,0,0,0};
        #pragma unroll
        for (int ky = 0; ky < 8; ++ky) {
            const float* rp = &bufB[(y0 + ky)*72 + x0];
            float in[16] __attribute__((aligned(16)));
            *(f4*)&in[0]  = *(const f4*)&rp[0];
            *(f4*)&in[4]  = *(const f4*)&rp[4];
            *(f4*)&in[8]  = *(const f4*)&rp[8];
            *(f4*)&in[12] = *(const f4*)&rp[12];
            if (ky < 7) {
                #pragma unroll
                for (int kx = 0; kx < 7; ++kx) {
                    float wv = wp[ky*7 + kx];
                    #pragma unroll
                    for (int cx = 0; cx < 8; ++cx) acc0[cx] += in[cx+kx] * wv;
                }
            }
            if (ky > 0) {
                #pragma unroll
                for (int kx = 0; kx < 7; ++kx) {
                    float wv = wp[(ky-1)*7 + kx];
                    #pragma unroll
                    for (int cx = 0; cx < 8; ++cx) acc1[cx] += in[cx+kx] * wv;
                }
            }
        }

        float A  = g1[c] * rsqrtf(va1[c] + BN_EPS);
        float Bb = (cb1[c] - mu1[c]) * A + be1[c];
        int h = c >> 3, c8 = c & 7;
        __hip_bfloat16* po = outb + ((size_t)h*784 + py*28)*8 + c8;
        #pragma unroll
        for (int j = 0; j < 4; ++j) {
            int px = xt*4 + j;
            float v00 = acc0[2*j]*A + Bb, v01 = acc0[2*j+1]*A + Bb;
            float v10 = acc1[2*j]*A + Bb, v11 = acc1[2*j+1]*A + Bb;
            float p = fmaxf(fmaxf(fmaxf(v00, v01), fmaxf(v10, v11)), 0.f);
            po[px*8] = __float2bfloat16(p);
        }
    }
}

// ---------------------------------------------------------------------------
// K_wprep: conv2 weights fp32 [30][15][7][7] -> bf16 [tap50][h2][co32][c8]
// ---------------------------------------------------------------------------
__global__ __launch_bounds__(256) void k_wprep(
    const float* __restrict__ w2, __hip_bfloat16* __restrict__ wbf)
{
    int i = blockIdx.x*256 + threadIdx.x;
    if (i >= 25600) return;
    int c8 = i & 7, co = (i >> 3) & 31, h = (i >> 8) & 1, tap = i >> 9;
    int ci = h*8 + c8;
    float v = 0.f;
    if (tap < 49 && ci < 15 && co < 30)
        v = w2[((co*15 + ci)*7 + tap/7)*7 + (tap%7)];
    wbf[i] = __float2bfloat16(v);
}

// ---------------------------------------------------------------------------
// K_wprep_fc1: fc1 weights fp32 [200][3630] -> bf16 [208][3840] zero-padded
// ---------------------------------------------------------------------------
__global__ __launch_bounds__(256) void k_wprep_fc1(
    const float* __restrict__ w, __hip_bfloat16* __restrict__ wb)
{
    int i = blockIdx.x*256 + threadIdx.x;
    if (i >= 208*3840) return;
    int n = i / 3840, k = i - n*3840;
    float v = (n < 200 && k < 3630) ? w[(size_t)n*3630 + k] : 0.f;
    wb[i] = __float2bfloat16(v);
}

// ---------------------------------------------------------------------------
// K2: conv2 implicit GEMM (mfma 16x16x32 bf16) + BN/ReLU/pool -> bf16 padded
// ---------------------------------------------------------------------------
__global__ __launch_bounds__(512, 4) void k_conv2(
    const ushort* __restrict__ pool1u, const ushort* __restrict__ wbfu,
    const float* __restrict__ cb2, const float* __restrict__ g2,
    const float* __restrict__ be2, const float* __restrict__ mu2,
    const float* __restrict__ va2, __hip_bfloat16* __restrict__ pool2b)
{
    __shared__ ushort img_s[12544];   // [h2][p784][c8]
    __shared__ ushort bs_s[25600];    // [tap50][h2][co32][c8]

    const int tid = threadIdx.x;
    const int b = blockIdx.x;

    {
        const f4* src = (const f4*)(pool1u + (size_t)b * 12544);
        f4* dst = (f4*)img_s;
        for (int i = tid; i < 1568; i += 512) dst[i] = src[i];
        const f4* wsrc = (const f4*)wbfu;
        f4* wdst = (f4*)bs_s;
        for (int i = tid; i < 3200; i += 512) wdst[i] = wsrc[i];
    }

    // zero the K-pad region of this row of pool2 (disjoint from epilogue)
    if (tid < 210)
        pool2b[(size_t)b*3840 + 3630 + tid] = __float2bfloat16(0.f);

    __syncthreads();

    const int l  = tid & 63;
    const int wv = tid >> 6;
    const int n16 = l & 15;
    const int Q4  = l >> 4;
    const int h   = Q4 & 1;
    const int qh  = Q4 >> 1;

    int Abase[4];
    #pragma unroll
    for (int mf = 0; mf < 4; ++mf) {
        int P  = wv*64 + mf*16 + n16;
        int Pc = P < 483 ? P : 483;
        int pr = Pc >> 2, sb = Pc & 3;
        int py = pr / 11, px = pr - py*11;
        int oy = 2*py + (sb >> 1), ox = 2*px + (sb & 1);
        Abase[mf] = (h*784 + oy*28 + ox) * 16;
    }
    const int Bb0 = qh*1024 + h*512 + n16*16;
    const int Bb1 = Bb0 + 256;

    const char* imgc = (const char*)img_s;
    const char* bsc  = (const char*)bs_s;

    f32x4 acc[4][2];
    #pragma unroll
    for (int mf = 0; mf < 4; ++mf)
        #pragma unroll
        for (int nf = 0; nf < 2; ++nf)
            acc[mf][nf] = (f32x4){0.f, 0.f, 0.f, 0.f};

    #pragma unroll
    for (int t = 0; t < 25; ++t) {
        const int tap0 = 2*t;
        const int tap1 = (2*t + 1 <= 48) ? 2*t + 1 : 48;
        const int o0 = ((tap0/7)*28 + tap0%7) * 16;
        const int o1 = ((tap1/7)*28 + tap1%7) * 16;
        const int offA = qh ? o1 : o0;

        s8v a[4], bf[2];
        #pragma unroll
        for (int mf = 0; mf < 4; ++mf)
            a[mf] = *(const s8v*)(imgc + (Abase[mf] + offA));
        bf[0] = *(const s8v*)(bsc + (Bb0 + t*2048));
        bf[1] = *(const s8v*)(bsc + (Bb1 + t*2048));

        #pragma unroll
        for (int mf = 0; mf < 4; ++mf)
            #pragma unroll
            for (int nf = 0; nf < 2; ++nf)
                acc[mf][nf] = __builtin_amdgcn_mfma_f32_16x16x32_bf16(
                    a[mf], bf[nf], acc[mf][nf], 0, 0, 0);
    }

    #pragma unroll
    for (int nf = 0; nf < 2; ++nf) {
        int co = nf*16 + n16;
        if (co >= 30) continue;
        float A  = g2[co] * rsqrtf(va2[co] + BN_EPS);
        float Bb = (cb2[co] - mu2[co]) * A + be2[co];
        __hip_bfloat16* outp = pool2b + (size_t)b*3840 + co*121;
        #pragma unroll
        for (int mf = 0; mf < 4; ++mf) {
            int pair = wv*16 + mf*4 + Q4;
            if (pair < 121) {
                f32x4 v = acc[mf][nf];
                float m01 = fmaxf(v[0]*A + Bb, v[1]*A + Bb);
                float m23 = fmaxf(v[2]*A + Bb, v[3]*A + Bb);
                outp[pair] = __float2bfloat16(fmaxf(fmaxf(m01, m23), 0.f));
            }
        }
    }
}

// ---------------------------------------------------------------------------
// K3a: fc1 bf16 MFMA GEMM. C[2048,208] = A[2048,3840] * W[208,3840]^T.
// grid 256 = 32 Mtiles(64) x 8 Ksplits(480). block 4 waves; wave = 1 Mfrag x
// 13 Nfrags, fragments direct from global (L2-resident), 15 K-steps of 32.
// ---------------------------------------------------------------------------
__global__ __launch_bounds__(256) void k_fc1(
    const ushort* __restrict__ Ab, const ushort* __restrict__ Wb,
    float* __restrict__ part)
{
    const int tid = threadIdx.x;
    const int bid = blockIdx.x;
    const int ks = bid & 7, mt = bid >> 3;
    const int m0 = mt * 64;
    const int k0 = ks * 480;
    const int wv = tid >> 6, l = tid & 63;
    const int n16 = l & 15, Q4 = l >> 4;

    const ushort* Arow = Ab + (size_t)(m0 + wv*16 + n16) * 3840 + k0 + Q4*8;
    const ushort* Wrow = Wb + (size_t)n16 * 3840 + k0 + Q4*8;

    f32x4 acc[13];
    #pragma unroll
    for (int nf = 0; nf < 13; ++nf) acc[nf] = (f32x4){0.f,0.f,0.f,0.f};

    #pragma unroll 1
    for (int t = 0; t < 15; ++t) {
        s8v a = *(const s8v*)(Arow + t*32);
        s8v bf[13];
        #pragma unroll
        for (int nf = 0; nf < 13; ++nf)
            bf[nf] = *(const s8v*)(Wrow + (size_t)nf*16*3840 + t*32);
        #pragma unroll
        for (int nf = 0; nf < 13; ++nf)
            acc[nf] = __builtin_amdgcn_mfma_f32_16x16x32_bf16(a, bf[nf], acc[nf], 0, 0, 0);
    }

    // C/D: col = lane&15 -> n16, row = Q4*4 + r
    float* dst = part + ((size_t)ks*2048 + m0 + wv*16 + Q4*4) * 208 + n16;
    #pragma unroll
    for (int nf = 0; nf < 13; ++nf)
        #pragma unroll
        for (int r = 0; r < 4; ++r)
            dst[(size_t)r*208 + nf*16] = acc[nf][r];
}

// ---------------------------------------------------------------------------
// K3b: sum 8 partials + bias + ReLU, fc2 + bias + sigmoid -> float32
// ---------------------------------------------------------------------------
__global__ __launch_bounds__(256) void k_fc2(
    const float* __restrict__ part, const float* __restrict__ fb1,
    const float* __restrict__ W2, const float* __restrict__ fb2,
    float* __restrict__ out)
{
    int b = blockIdx.x * 4 + (threadIdx.x >> 6);
    int l = threadIdx.x & 63;
    float a0 = 0.f, a1 = 0.f;
    #pragma unroll
    for (int j = 0; j < 4; ++j) {
        int n = l + j*64;
        if (n < 200) {
            float v = fb1[n];
            #pragma unroll
            for (int ks = 0; ks < 8; ++ks)
                v += part[((size_t)ks*2048 + b)*208 + n];
            v = fmaxf(v, 0.f);
            a0 += v * W2[n];
            a1 += v * W2[200 + n];
        }
    }
    #pragma unroll
    for (int m = 32; m >= 1; m >>= 1) {
        a0 += __shfl_xor(a0, m);
        a1 += __shfl_xor(a1, m);
    }
    if (l == 0) {
        float z0 = a0 + fb2[0], z1 = a1 + fb2[1];
        out[b*2 + 0] = 1.f / (1.f + expf(-z0));
        out[b*2 + 1] = 1.f / (1.f + expf(-z1));
    }
}

// ---------------------------------------------------------------------------
extern "C" void kernel_launch(void* const* d_in, const int* in_sizes, int n_in,
                              void* d_out, int out_size, void* d_ws, size_t ws_size,
                              hipStream_t stream)
{
    const float* x         = (const float*)d_in[0];
    const float* log_s     = (const float*)d_in[1];
    const float* log_alpha = (const float*)d_in[2];
    const float* log_delta = (const float*)d_in[3];
    const float* log_r     = (const float*)d_in[4];
    const float* conv1_w   = (const float*)d_in[5];
    const float* conv1_b   = (const float*)d_in[6];
    const float* bn1_g     = (const float*)d_in[7];
    const float* bn1_b     = (const float*)d_in[8];
    const float* bn1_m     = (const float*)d_in[9];
    const float* bn1_v     = (const float*)d_in[10];
    const float* conv2_w   = (const float*)d_in[11];
    const float* conv2_b   = (const float*)d_in[12];
    const float* bn2_g     = (const float*)d_in[13];
    const float* bn2_b     = (const float*)d_in[14];
    const float* bn2_m     = (const float*)d_in[15];
    const float* bn2_v     = (const float*)d_in[16];
    const float* fc1_w     = (const float*)d_in[17];
    const float* fc1_b     = (const float*)d_in[18];
    const float* fc2_w     = (const float*)d_in[19];
    const float* fc2_b     = (const float*)d_in[20];

    char* wsb = (char*)d_ws;
    __hip_bfloat16* pool1  = (__hip_bfloat16*)(wsb + POOL1_OFF);
    __hip_bfloat16* wbf    = (__hip_bfloat16*)(wsb + WBF_OFF);
    __hip_bfloat16* wfc1b  = (__hip_bfloat16*)(wsb + WFC1_OFF);
    __hip_bfloat16* pool2b = (__hip_bfloat16*)(wsb + POOL2_OFF);
    float* part            = (float*)(wsb + PART_OFF);

    k_wprep<<<100, 256, 0, stream>>>(conv2_w, wbf);
    k_wprep_fc1<<<3120, 256, 0, stream>>>(fc1_w, wfc1b);
    k_pcen_conv1<<<2048, 256, 0, stream>>>(x, log_s, log_alpha, log_delta, log_r,
                                           conv1_w, conv1_b, bn1_g, bn1_b, bn1_m, bn1_v,
                                           pool1);
    k_conv2<<<2048, 512, 0, stream>>>((const ushort*)pool1, (const ushort*)wbf,
                                      conv2_b, bn2_g, bn2_b, bn2_m, bn2_v, pool2b);
    k_fc1<<<256, 256, 0, stream>>>((const ushort*)pool2b, (const ushort*)wfc1b, part);
    k_fc2<<<512, 256, 0, stream>>>(part, fc1_b, fc2_w, fc2_b, (float*)d_out);
}

// Round 5
// 254.730 us; speedup vs baseline: 8.8028x; 1.3465x over previous
//
#include <hip/hip_runtime.h>
#include <hip/hip_bf16.h>

typedef float f4 __attribute__((ext_vector_type(4)));
typedef float f32x4 __attribute__((ext_vector_type(4)));
typedef short s8v __attribute__((ext_vector_type(8)));

#define BN_EPS   1e-5f
#define PCEN_EPS 1e-6f

// ---- workspace byte layout (all offsets 16B-aligned) ----
#define POOL1_OFF   0UL
#define POOL1_BYTES (2048UL*25088)                 // bf16 [b][h2][y28][x28][c8]
#define WBF_OFF     (POOL1_OFF + POOL1_BYTES)
#define WBF_BYTES   (50UL*2*32*8*2)                // conv2 W bf16: 51200 B
#define WFC1_OFF    (WBF_OFF + WBF_BYTES)
#define WFC1_BYTES  (208UL*3840*2)                 // fc1 W bf16 padded
#define W1EX_OFF    (WFC1_OFF + WFC1_BYTES)
#define W1EX_BYTES  (8UL*16*136*2)                 // conv1 r-shifted W bf16: 34816 B
#define POOL2_OFF   (W1EX_OFF + W1EX_BYTES)
#define POOL2_BYTES (2048UL*3840*2)                // bf16 [b][3840] (K-padded)
#define PART_OFF    (POOL2_OFF + POOL2_BYTES)
#define PART_BYTES  (8UL*2048*208*4)               // fp32 [ks8][b][208]

static __device__ inline ushort f2bu(float v) {
    __hip_bfloat16 h = __float2bfloat16(v);
    return *(ushort*)&h;
}

// ---------------------------------------------------------------------------
// K_wprep_c1: conv1 weights fp32 [15][1][7][7] -> bf16 w1ex[r8][n16][k136]
// k = ky*16 + kx' (K=128 used, 136 = +pad for LDS bank spread);
// value = w1[n][ky][kx'-r] when ky<7, 0<=kx'-r<=6, n<15; else 0.
// ---------------------------------------------------------------------------
__global__ __launch_bounds__(256) void k_wprep_c1(
    const float* __restrict__ w1, __hip_bfloat16* __restrict__ w1ex)
{
    int i = blockIdx.x*256 + threadIdx.x;
    if (i >= 8*16*136) return;
    int r = i / 2176, rem = i - r*2176;
    int n = rem / 136, k = rem - n*136;
    float v = 0.f;
    if (k < 128) {
        int ky = k >> 4, kx = (k & 15) - r;
        if (ky < 7 && kx >= 0 && kx <= 6 && n < 15)
            v = w1[n*49 + ky*7 + kx];
    }
    w1ex[i] = __float2bfloat16(v);
}

// ---------------------------------------------------------------------------
// K1: PCEN + conv1 via MFMA (r-shift trick) + BN + ReLU + 2x2 pool
// block = 1 image (2048 x 256 = 4 waves). Wave u owns x-residues r=2u,2u+1.
// Per wave: 28 iters of (a 0..6, y0 {0,16,32,48}): 4 A-ds_read_b128 -> 8 MFMA.
// ---------------------------------------------------------------------------
__global__ __launch_bounds__(256) void k_pcen_conv1(
    const float* __restrict__ x,
    const float* __restrict__ log_s, const float* __restrict__ log_alpha,
    const float* __restrict__ log_delta, const float* __restrict__ log_r,
    const ushort* __restrict__ w1ex, const float* __restrict__ cb1,
    const float* __restrict__ g1, const float* __restrict__ be1,
    const float* __restrict__ mu1, const float* __restrict__ va1,
    __hip_bfloat16* __restrict__ pool1)
{
    __shared__ union {
        float  bufA[64*65];        // 16640 B (PCEN workspace)
        ushort Bs[8*16*136];       // 34816 B (staged weights, after PCEN)
    } u;
    __shared__ ushort img_s[64*72 + 520];  // bf16 image, stride 72 (+OOB-read pad)

    const int tid = threadIdx.x;
    const int b = blockIdx.x;

    // ---- 1) load image (coalesced float4) ----
    const f4* xin = (const f4*)(x + (size_t)b * 4096);
    for (int i = tid; i < 1024; i += 256) {
        f4 v = xin[i];
        int flat = i * 4, h = flat >> 6, w = flat & 63;
        float* p = &u.bufA[h*65 + w];
        p[0] = v[0]; p[1] = v[1]; p[2] = v[2]; p[3] = v[3];
    }
    __syncthreads();

    // ---- 2) PCEN scan along w (one lane per h row) ----
    if (tid < 64) {
        const float s     = expf(log_s[0]);
        const float alpha = expf(log_alpha[0]);
        const float delta = expf(log_delta[0]);
        const float r     = expf(log_r[0]);
        const float dr    = expf(r * logf(delta));
        float* row = &u.bufA[tid*65];
        float m = 0.f;
        for (int w = 0; w < 64; ++w) {
            float xv = row[w];
            m = (w == 0) ? s * xv : (1.f - s) * m + s * xv;
            float t = xv * expf(-alpha * logf(m + PCEN_EPS)) + delta;
            row[w] = expf(r * logf(t)) - dr;
        }
    }
    __syncthreads();

    // ---- 3) convert to bf16 image, stride 72 ----
    for (int i = tid; i < 2048; i += 256) {
        int y = i >> 5, xp = (i & 31) * 2;
        ushort2 pk;
        pk.x = f2bu(u.bufA[y*65 + xp]);
        pk.y = f2bu(u.bufA[y*65 + xp + 1]);
        *(ushort2*)&img_s[y*72 + xp] = pk;
    }
    __syncthreads();

    // ---- 4) stage r-shifted weights (overwrites bufA) + pool1 pad plane ----
    {
        const f4* ws = (const f4*)w1ex;
        f4* wd = (f4*)u.Bs;
        for (int i = tid; i < 2176; i += 256) wd[i] = ws[i];
    }
    __hip_bfloat16* outb = pool1 + (size_t)b * 12544;
    for (int p = tid; p < 784; p += 256)
        outb[(784 + p)*8 + 7] = __float2bfloat16(0.f);
    __syncthreads();

    // ---- 5) MFMA conv + fused BN/pool/ReLU ----
    const int l   = tid & 63;
    const int wv  = tid >> 6;          // r-pair index u: r = 2u, 2u+1
    const int n16 = l & 15;
    const int Q4  = l >> 4;

    // B fragments for this wave's two residues, all 4 k-steps
    s8v Bf[2][4];
    #pragma unroll
    for (int rr = 0; rr < 2; ++rr)
        #pragma unroll
        for (int s = 0; s < 4; ++s)
            Bf[rr][s] = *(const s8v*)&u.Bs[((wv*2 + rr)*16 + n16)*136 + s*32 + Q4*8];

    // BN constants for channel n16
    const int ch = n16;
    float An = 0.f, Bn = 0.f;
    if (ch < 15) {
        An = g1[ch] * rsqrtf(va1[ch] + BN_EPS);
        Bn = (cb1[ch] - mu1[ch]) * An + be1[ch];
    }
    const int h8 = ch >> 3, c8 = ch & 7;
    const int rowA = l & 15;           // A-operand m index

    #pragma unroll 1
    for (int it = 0; it < 28; ++it) {
        int a  = it % 7;
        int y0 = (it / 7) * 16;

        s8v Aa[4];
        #pragma unroll
        for (int s = 0; s < 4; ++s)
            Aa[s] = *(const s8v*)&img_s[(y0 + rowA + s*2 + (Q4 >> 1))*72
                                        + a*8 + (Q4 & 1)*8];

        f32x4 ac0 = (f32x4){0.f,0.f,0.f,0.f};
        f32x4 ac1 = (f32x4){0.f,0.f,0.f,0.f};
        #pragma unroll
        for (int s = 0; s < 4; ++s) {
            ac0 = __builtin_amdgcn_mfma_f32_16x16x32_bf16(Aa[s], Bf[0][s], ac0, 0, 0, 0);
            ac1 = __builtin_amdgcn_mfma_f32_16x16x32_bf16(Aa[s], Bf[1][s], ac1, 0, 0, 0);
        }

        // epilogue: C row m = Q4*4 + reg -> y = y0 + m; pool pairs = reg (0,1),(2,3)
        if (ch < 15 && y0 + Q4*4 < 56) {
            int pxo = a*4 + wv;                    // pooled x
            int py  = (y0 >> 1) + Q4*2;            // pooled y of reg pair (0,1)
            float v0 = ac0[0]*An + Bn, v1 = ac0[1]*An + Bn;
            float v2 = ac1[0]*An + Bn, v3 = ac1[1]*An + Bn;
            float p0 = fmaxf(fmaxf(fmaxf(v0, v1), fmaxf(v2, v3)), 0.f);
            outb[h8*6272 + (py*28 + pxo)*8 + c8] = __float2bfloat16(p0);
            float w0 = ac0[2]*An + Bn, w1v = ac0[3]*An + Bn;
            float w2 = ac1[2]*An + Bn, w3 = ac1[3]*An + Bn;
            float p1 = fmaxf(fmaxf(fmaxf(w0, w1v), fmaxf(w2, w3)), 0.f);
            outb[h8*6272 + ((py+1)*28 + pxo)*8 + c8] = __float2bfloat16(p1);
        }
    }
}

// ---------------------------------------------------------------------------
// K_wprep: conv2 weights fp32 [30][15][7][7] -> bf16 [tap50][h2][co32][c8]
// ---------------------------------------------------------------------------
__global__ __launch_bounds__(256) void k_wprep(
    const float* __restrict__ w2, __hip_bfloat16* __restrict__ wbf)
{
    int i = blockIdx.x*256 + threadIdx.x;
    if (i >= 25600) return;
    int c8 = i & 7, co = (i >> 3) & 31, h = (i >> 8) & 1, tap = i >> 9;
    int ci = h*8 + c8;
    float v = 0.f;
    if (tap < 49 && ci < 15 && co < 30)
        v = w2[((co*15 + ci)*7 + tap/7)*7 + (tap%7)];
    wbf[i] = __float2bfloat16(v);
}

// ---------------------------------------------------------------------------
// K_wprep_fc1: fc1 weights fp32 [200][3630] -> bf16 [208][3840] zero-padded
// ---------------------------------------------------------------------------
__global__ __launch_bounds__(256) void k_wprep_fc1(
    const float* __restrict__ w, __hip_bfloat16* __restrict__ wb)
{
    int i = blockIdx.x*256 + threadIdx.x;
    if (i >= 208*3840) return;
    int n = i / 3840, k = i - n*3840;
    float v = (n < 200 && k < 3630) ? w[(size_t)n*3630 + k] : 0.f;
    wb[i] = __float2bfloat16(v);
}

// ---------------------------------------------------------------------------
// K2: conv2 implicit GEMM (mfma 16x16x32 bf16) + BN/ReLU/pool -> bf16 padded
// ---------------------------------------------------------------------------
__global__ __launch_bounds__(512, 4) void k_conv2(
    const ushort* __restrict__ pool1u, const ushort* __restrict__ wbfu,
    const float* __restrict__ cb2, const float* __restrict__ g2,
    const float* __restrict__ be2, const float* __restrict__ mu2,
    const float* __restrict__ va2, __hip_bfloat16* __restrict__ pool2b)
{
    __shared__ ushort img_s[12544];   // [h2][p784][c8]
    __shared__ ushort bs_s[25600];    // [tap50][h2][co32][c8]

    const int tid = threadIdx.x;
    const int b = blockIdx.x;

    {
        const f4* src = (const f4*)(pool1u + (size_t)b * 12544);
        f4* dst = (f4*)img_s;
        for (int i = tid; i < 1568; i += 512) dst[i] = src[i];
        const f4* wsrc = (const f4*)wbfu;
        f4* wdst = (f4*)bs_s;
        for (int i = tid; i < 3200; i += 512) wdst[i] = wsrc[i];
    }

    if (tid < 210)
        pool2b[(size_t)b*3840 + 3630 + tid] = __float2bfloat16(0.f);

    __syncthreads();

    const int l  = tid & 63;
    const int wv = tid >> 6;
    const int n16 = l & 15;
    const int Q4  = l >> 4;
    const int h   = Q4 & 1;
    const int qh  = Q4 >> 1;

    int Abase[4];
    #pragma unroll
    for (int mf = 0; mf < 4; ++mf) {
        int P  = wv*64 + mf*16 + n16;
        int Pc = P < 483 ? P : 483;
        int pr = Pc >> 2, sb = Pc & 3;
        int py = pr / 11, px = pr - py*11;
        int oy = 2*py + (sb >> 1), ox = 2*px + (sb & 1);
        Abase[mf] = (h*784 + oy*28 + ox) * 16;
    }
    const int Bb0 = qh*1024 + h*512 + n16*16;
    const int Bb1 = Bb0 + 256;

    const char* imgc = (const char*)img_s;
    const char* bsc  = (const char*)bs_s;

    f32x4 acc[4][2];
    #pragma unroll
    for (int mf = 0; mf < 4; ++mf)
        #pragma unroll
        for (int nf = 0; nf < 2; ++nf)
            acc[mf][nf] = (f32x4){0.f, 0.f, 0.f, 0.f};

    #pragma unroll
    for (int t = 0; t < 25; ++t) {
        const int tap0 = 2*t;
        const int tap1 = (2*t + 1 <= 48) ? 2*t + 1 : 48;
        const int o0 = ((tap0/7)*28 + tap0%7) * 16;
        const int o1 = ((tap1/7)*28 + tap1%7) * 16;
        const int offA = qh ? o1 : o0;

        s8v a[4], bf[2];
        #pragma unroll
        for (int mf = 0; mf < 4; ++mf)
            a[mf] = *(const s8v*)(imgc + (Abase[mf] + offA));
        bf[0] = *(const s8v*)(bsc + (Bb0 + t*2048));
        bf[1] = *(const s8v*)(bsc + (Bb1 + t*2048));

        #pragma unroll
        for (int mf = 0; mf < 4; ++mf)
            #pragma unroll
            for (int nf = 0; nf < 2; ++nf)
                acc[mf][nf] = __builtin_amdgcn_mfma_f32_16x16x32_bf16(
                    a[mf], bf[nf], acc[mf][nf], 0, 0, 0);
    }

    #pragma unroll
    for (int nf = 0; nf < 2; ++nf) {
        int co = nf*16 + n16;
        if (co >= 30) continue;
        float A  = g2[co] * rsqrtf(va2[co] + BN_EPS);
        float Bb = (cb2[co] - mu2[co]) * A + be2[co];
        __hip_bfloat16* outp = pool2b + (size_t)b*3840 + co*121;
        #pragma unroll
        for (int mf = 0; mf < 4; ++mf) {
            int pair = wv*16 + mf*4 + Q4;
            if (pair < 121) {
                f32x4 v = acc[mf][nf];
                float m01 = fmaxf(v[0]*A + Bb, v[1]*A + Bb);
                float m23 = fmaxf(v[2]*A + Bb, v[3]*A + Bb);
                outp[pair] = __float2bfloat16(fmaxf(fmaxf(m01, m23), 0.f));
            }
        }
    }
}

// ---------------------------------------------------------------------------
// K3a: fc1 bf16 MFMA GEMM. C[2048,208] = A[2048,3840] * W[208,3840]^T.
// grid 256 = 32 Mtiles(64) x 8 Ksplits(480). block 4 waves; wave = 1 Mfrag x
// 13 Nfrags, fragments direct from global (L2-resident), 15 K-steps of 32.
// ---------------------------------------------------------------------------
__global__ __launch_bounds__(256) void k_fc1(
    const ushort* __restrict__ Ab, const ushort* __restrict__ Wb,
    float* __restrict__ part)
{
    const int tid = threadIdx.x;
    const int bid = blockIdx.x;
    const int ks = bid & 7, mt = bid >> 3;
    const int m0 = mt * 64;
    const int k0 = ks * 480;
    const int wv = tid >> 6, l = tid & 63;
    const int n16 = l & 15, Q4 = l >> 4;

    const ushort* Arow = Ab + (size_t)(m0 + wv*16 + n16) * 3840 + k0 + Q4*8;
    const ushort* Wrow = Wb + (size_t)n16 * 3840 + k0 + Q4*8;

    f32x4 acc[13];
    #pragma unroll
    for (int nf = 0; nf < 13; ++nf) acc[nf] = (f32x4){0.f,0.f,0.f,0.f};

    #pragma unroll 1
    for (int t = 0; t < 15; ++t) {
        s8v a = *(const s8v*)(Arow + t*32);
        s8v bf[13];
        #pragma unroll
        for (int nf = 0; nf < 13; ++nf)
            bf[nf] = *(const s8v*)(Wrow + (size_t)nf*16*3840 + t*32);
        #pragma unroll
        for (int nf = 0; nf < 13; ++nf)
            acc[nf] = __builtin_amdgcn_mfma_f32_16x16x32_bf16(a, bf[nf], acc[nf], 0, 0, 0);
    }

    float* dst = part + ((size_t)ks*2048 + m0 + wv*16 + Q4*4) * 208 + n16;
    #pragma unroll
    for (int nf = 0; nf < 13; ++nf)
        #pragma unroll
        for (int r = 0; r < 4; ++r)
            dst[(size_t)r*208 + nf*16] = acc[nf][r];
}

// ---------------------------------------------------------------------------
// K3b: sum 8 partials + bias + ReLU, fc2 + bias + sigmoid -> float32
// ---------------------------------------------------------------------------
__global__ __launch_bounds__(256) void k_fc2(
    const float* __restrict__ part, const float* __restrict__ fb1,
    const float* __restrict__ W2, const float* __restrict__ fb2,
    float* __restrict__ out)
{
    int b = blockIdx.x * 4 + (threadIdx.x >> 6);
    int l = threadIdx.x & 63;
    float a0 = 0.f, a1 = 0.f;
    #pragma unroll
    for (int j = 0; j < 4; ++j) {
        int n = l + j*64;
        if (n < 200) {
            float v = fb1[n];
            #pragma unroll
            for (int ks = 0; ks < 8; ++ks)
                v += part[((size_t)ks*2048 + b)*208 + n];
            v = fmaxf(v, 0.f);
            a0 += v * W2[n];
            a1 += v * W2[200 + n];
        }
    }
    #pragma unroll
    for (int m = 32; m >= 1; m >>= 1) {
        a0 += __shfl_xor(a0, m);
        a1 += __shfl_xor(a1, m);
    }
    if (l == 0) {
        float z0 = a0 + fb2[0], z1 = a1 + fb2[1];
        out[b*2 + 0] = 1.f / (1.f + expf(-z0));
        out[b*2 + 1] = 1.f / (1.f + expf(-z1));
    }
}

// ---------------------------------------------------------------------------
extern "C" void kernel_launch(void* const* d_in, const int* in_sizes, int n_in,
                              void* d_out, int out_size, void* d_ws, size_t ws_size,
                              hipStream_t stream)
{
    const float* x         = (const float*)d_in[0];
    const float* log_s     = (const float*)d_in[1];
    const float* log_alpha = (const float*)d_in[2];
    const float* log_delta = (const float*)d_in[3];
    const float* log_r     = (const float*)d_in[4];
    const float* conv1_w   = (const float*)d_in[5];
    const float* conv1_b   = (const float*)d_in[6];
    const float* bn1_g     = (const float*)d_in[7];
    const float* bn1_b     = (const float*)d_in[8];
    const float* bn1_m     = (const float*)d_in[9];
    const float* bn1_v     = (const float*)d_in[10];
    const float* conv2_w   = (const float*)d_in[11];
    const float* conv2_b   = (const float*)d_in[12];
    const float* bn2_g     = (const float*)d_in[13];
    const float* bn2_b     = (const float*)d_in[14];
    const float* bn2_m     = (const float*)d_in[15];
    const float* bn2_v     = (const float*)d_in[16];
    const float* fc1_w     = (const float*)d_in[17];
    const float* fc1_b     = (const float*)d_in[18];
    const float* fc2_w     = (const float*)d_in[19];
    const float* fc2_b     = (const float*)d_in[20];

    char* wsb = (char*)d_ws;
    __hip_bfloat16* pool1  = (__hip_bfloat16*)(wsb + POOL1_OFF);
    __hip_bfloat16* wbf    = (__hip_bfloat16*)(wsb + WBF_OFF);
    __hip_bfloat16* wfc1b  = (__hip_bfloat16*)(wsb + WFC1_OFF);
    __hip_bfloat16* w1ex   = (__hip_bfloat16*)(wsb + W1EX_OFF);
    __hip_bfloat16* pool2b = (__hip_bfloat16*)(wsb + POOL2_OFF);
    float* part            = (float*)(wsb + PART_OFF);

    k_wprep_c1<<<68, 256, 0, stream>>>(conv1_w, w1ex);
    k_wprep<<<100, 256, 0, stream>>>(conv2_w, wbf);
    k_wprep_fc1<<<3120, 256, 0, stream>>>(fc1_w, wfc1b);
    k_pcen_conv1<<<2048, 256, 0, stream>>>(x, log_s, log_alpha, log_delta, log_r,
                                           (const ushort*)w1ex, conv1_b,
                                           bn1_g, bn1_b, bn1_m, bn1_v, pool1);
    k_conv2<<<2048, 512, 0, stream>>>((const ushort*)pool1, (const ushort*)wbf,
                                      conv2_b, bn2_g, bn2_b, bn2_m, bn2_v, pool2b);
    k_fc1<<<256, 256, 0, stream>>>((const ushort*)pool2b, (const ushort*)wfc1b, part);
    k_fc2<<<512, 256, 0, stream>>>(part, fc1_b, fc2_w, fc2_b, (float*)d_out);
}

// Round 6
// 227.201 us; speedup vs baseline: 9.8694x; 1.1212x over previous
//
#include <hip/hip_runtime.h>
#include <hip/hip_bf16.h>

typedef float f4 __attribute__((ext_vector_type(4)));
typedef float f32x4 __attribute__((ext_vector_type(4)));
typedef short s8v __attribute__((ext_vector_type(8)));
typedef unsigned short u16x8 __attribute__((ext_vector_type(8)));

#define BN_EPS   1e-5f
#define PCEN_EPS 1e-6f

// ---- workspace byte layout (all offsets 16B-aligned) ----
#define POOL1_OFF   0UL
#define POOL1_BYTES (2048UL*25088)                 // bf16 [b][h2][y28][x28][c8]
#define WBF_OFF     (POOL1_OFF + POOL1_BYTES)
#define WBF_BYTES   (50UL*2*32*8*2)                // conv2 W bf16: 51200 B
#define WFC1_OFF    (WBF_OFF + WBF_BYTES)
#define WFC1_BYTES  (208UL*3840*2)                 // fc1 W bf16 padded
#define W1EX_OFF    (WFC1_OFF + WFC1_BYTES)
#define W1EX_BYTES  (8UL*16*136*2)                 // conv1 r-shifted W bf16: 34816 B
#define POOL2_OFF   (W1EX_OFF + W1EX_BYTES)
#define POOL2_BYTES (2048UL*3840*2)                // bf16 [b][3840] (K-padded)
#define PART_OFF    (POOL2_OFF + POOL2_BYTES)
#define PART_BYTES  (8UL*2048*208*4)               // fp32 [ks8][b][208]

static __device__ inline ushort f2bu(float v) {
    __hip_bfloat16 h = __float2bfloat16(v);
    return *(ushort*)&h;
}

// ---------------------------------------------------------------------------
// K_wprep_c1: conv1 weights fp32 [15][1][7][7] -> bf16 w1ex[r8][n16][k136]
// k = ky*16 + kx'; value = w1[n][ky][kx'-r] when ky<7, 0<=kx'-r<=6, n<15.
// ---------------------------------------------------------------------------
__global__ __launch_bounds__(256) void k_wprep_c1(
    const float* __restrict__ w1, __hip_bfloat16* __restrict__ w1ex)
{
    int i = blockIdx.x*256 + threadIdx.x;
    if (i >= 8*16*136) return;
    int r = i / 2176, rem = i - r*2176;
    int n = rem / 136, k = rem - n*136;
    float v = 0.f;
    if (k < 128) {
        int ky = k >> 4, kx = (k & 15) - r;
        if (ky < 7 && kx >= 0 && kx <= 6 && n < 15)
            v = w1[n*49 + ky*7 + kx];
    }
    w1ex[i] = __float2bfloat16(v);
}

// ---------------------------------------------------------------------------
// K1: PCEN (parallel segmented scan, all 256 threads) + conv1 via MFMA
// (r-shift trick) + BN + ReLU + 2x2 pool.  block = 1 image (2048 x 256).
// LDS = bf16 image only (10.3 KB).  Weights -> registers from global.
// ---------------------------------------------------------------------------
__global__ __launch_bounds__(256) void k_pcen_conv1(
    const float* __restrict__ x,
    const float* __restrict__ log_s, const float* __restrict__ log_alpha,
    const float* __restrict__ log_delta, const float* __restrict__ log_r,
    const ushort* __restrict__ w1ex, const float* __restrict__ cb1,
    const float* __restrict__ g1, const float* __restrict__ be1,
    const float* __restrict__ mu1, const float* __restrict__ va1,
    __hip_bfloat16* __restrict__ pool1)
{
    __shared__ ushort img_s[64*72 + 520];  // bf16 image, stride 72 (+OOB pad)

    const int tid = threadIdx.x;
    const int b = blockIdx.x;
    const int l   = tid & 63;
    const int wv  = tid >> 6;

    // ---- phase A: direct global load of 16 x's + parallel PCEN ----
    const int hrow = tid >> 2, jseg = tid & 3;
    float xs[16];
    {
        const f4* xr = (const f4*)(x + (size_t)b*4096 + hrow*64 + jseg*16);
        f4 v0 = xr[0], v1 = xr[1], v2 = xr[2], v3 = xr[3];
        *(f4*)&xs[0]  = v0; *(f4*)&xs[4]  = v1;
        *(f4*)&xs[8]  = v2; *(f4*)&xs[12] = v3;
    }
    const float s     = __expf(log_s[0]);
    const float alpha = __expf(log_alpha[0]);
    const float delta = __expf(log_delta[0]);
    const float r     = __expf(log_r[0]);
    const float dr    = __expf(r * __logf(delta));
    const float om    = 1.f - s;

    // local recurrence from m=0 -> segment offset B
    float m = 0.f;
    #pragma unroll
    for (int i = 0; i < 16; ++i) m = om*m + s*xs[i];

    // A16 = (1-s)^16
    float A16 = om; A16 *= A16; A16 *= A16; A16 *= A16; A16 *= A16;
    float A32 = A16 * A16;

    // inclusive segmented scan across the 4 lanes of this row
    float v = m;
    float p = __shfl_up(v, 1, 4); v += (jseg >= 1) ? A16*p : 0.f;
    p = __shfl_up(v, 2, 4);       v += (jseg >= 2) ? A32*p : 0.f;
    p = __shfl_up(v, 1, 4);
    float m_in = (jseg >= 1) ? p : 0.f;

    // re-run with true m_in, emit PCEN outputs as bf16
    ushort outp[16];
    m = m_in;
    #pragma unroll
    for (int i = 0; i < 16; ++i) {
        m = om*m + s*xs[i];
        float t = xs[i] * __expf(-alpha * __logf(m + PCEN_EPS)) + delta;
        outp[i] = f2bu(__expf(r * __logf(t)) - dr);
    }
    *(u16x8*)&img_s[hrow*72 + jseg*16]     = *(u16x8*)&outp[0];
    *(u16x8*)&img_s[hrow*72 + jseg*16 + 8] = *(u16x8*)&outp[8];

    // ---- weights: global (L2) -> registers; pool1 pad plane zero-fill ----
    const int n16 = l & 15;
    const int Q4  = l >> 4;
    s8v Bf[2][4];
    #pragma unroll
    for (int rr = 0; rr < 2; ++rr)
        #pragma unroll
        for (int ss = 0; ss < 4; ++ss)
            Bf[rr][ss] = *(const s8v*)&w1ex[((wv*2 + rr)*16 + n16)*136 + ss*32 + Q4*8];

    __hip_bfloat16* outb = pool1 + (size_t)b * 12544;
    for (int pz = tid; pz < 784; pz += 256)
        outb[(784 + pz)*8 + 7] = __float2bfloat16(0.f);

    __syncthreads();

    // ---- phase B: MFMA conv + fused BN/pool/ReLU ----
    const int ch = n16;
    float An = 0.f, Bn = 0.f;
    if (ch < 15) {
        An = g1[ch] * rsqrtf(va1[ch] + BN_EPS);
        Bn = (cb1[ch] - mu1[ch]) * An + be1[ch];
    }
    const int h8 = ch >> 3, c8 = ch & 7;
    const int rowA = l & 15;

    #pragma unroll 1
    for (int it = 0; it < 28; ++it) {
        int a  = it % 7;
        int y0 = (it / 7) * 16;

        s8v Aa[4];
        #pragma unroll
        for (int ss = 0; ss < 4; ++ss)
            Aa[ss] = *(const s8v*)&img_s[(y0 + rowA + ss*2 + (Q4 >> 1))*72
                                         + a*8 + (Q4 & 1)*8];

        f32x4 ac0 = (f32x4){0.f,0.f,0.f,0.f};
        f32x4 ac1 = (f32x4){0.f,0.f,0.f,0.f};
        #pragma unroll
        for (int ss = 0; ss < 4; ++ss) {
            ac0 = __builtin_amdgcn_mfma_f32_16x16x32_bf16(Aa[ss], Bf[0][ss], ac0, 0, 0, 0);
            ac1 = __builtin_amdgcn_mfma_f32_16x16x32_bf16(Aa[ss], Bf[1][ss], ac1, 0, 0, 0);
        }

        if (ch < 15 && y0 + Q4*4 < 56) {
            int pxo = a*4 + wv;
            int py  = (y0 >> 1) + Q4*2;
            float v0 = ac0[0]*An + Bn, v1 = ac0[1]*An + Bn;
            float v2 = ac1[0]*An + Bn, v3 = ac1[1]*An + Bn;
            float p0 = fmaxf(fmaxf(fmaxf(v0, v1), fmaxf(v2, v3)), 0.f);
            outb[h8*6272 + (py*28 + pxo)*8 + c8] = __float2bfloat16(p0);
            float w0 = ac0[2]*An + Bn, w1v = ac0[3]*An + Bn;
            float w2 = ac1[2]*An + Bn, w3 = ac1[3]*An + Bn;
            float p1 = fmaxf(fmaxf(fmaxf(w0, w1v), fmaxf(w2, w3)), 0.f);
            outb[h8*6272 + ((py+1)*28 + pxo)*8 + c8] = __float2bfloat16(p1);
        }
    }
}

// ---------------------------------------------------------------------------
// K_wprep: conv2 weights fp32 [30][15][7][7] -> bf16 [tap50][h2][co32][c8]
// ---------------------------------------------------------------------------
__global__ __launch_bounds__(256) void k_wprep(
    const float* __restrict__ w2, __hip_bfloat16* __restrict__ wbf)
{
    int i = blockIdx.x*256 + threadIdx.x;
    if (i >= 25600) return;
    int c8 = i & 7, co = (i >> 3) & 31, h = (i >> 8) & 1, tap = i >> 9;
    int ci = h*8 + c8;
    float v = 0.f;
    if (tap < 49 && ci < 15 && co < 30)
        v = w2[((co*15 + ci)*7 + tap/7)*7 + (tap%7)];
    wbf[i] = __float2bfloat16(v);
}

// ---------------------------------------------------------------------------
// K_wprep_fc1: fc1 weights fp32 [200][3630] -> bf16 [208][3840] zero-padded
// ---------------------------------------------------------------------------
__global__ __launch_bounds__(256) void k_wprep_fc1(
    const float* __restrict__ w, __hip_bfloat16* __restrict__ wb)
{
    int i = blockIdx.x*256 + threadIdx.x;
    if (i >= 208*3840) return;
    int n = i / 3840, k = i - n*3840;
    float v = (n < 200 && k < 3630) ? w[(size_t)n*3630 + k] : 0.f;
    wb[i] = __float2bfloat16(v);
}

// ---------------------------------------------------------------------------
// K2: conv2 implicit GEMM (mfma 16x16x32 bf16) + BN/ReLU/pool -> bf16 padded
// ---------------------------------------------------------------------------
__global__ __launch_bounds__(512, 4) void k_conv2(
    const ushort* __restrict__ pool1u, const ushort* __restrict__ wbfu,
    const float* __restrict__ cb2, const float* __restrict__ g2,
    const float* __restrict__ be2, const float* __restrict__ mu2,
    const float* __restrict__ va2, __hip_bfloat16* __restrict__ pool2b)
{
    __shared__ ushort img_s[12544];   // [h2][p784][c8]
    __shared__ ushort bs_s[25600];    // [tap50][h2][co32][c8]

    const int tid = threadIdx.x;
    const int b = blockIdx.x;

    {
        const f4* src = (const f4*)(pool1u + (size_t)b * 12544);
        f4* dst = (f4*)img_s;
        for (int i = tid; i < 1568; i += 512) dst[i] = src[i];
        const f4* wsrc = (const f4*)wbfu;
        f4* wdst = (f4*)bs_s;
        for (int i = tid; i < 3200; i += 512) wdst[i] = wsrc[i];
    }

    if (tid < 210)
        pool2b[(size_t)b*3840 + 3630 + tid] = __float2bfloat16(0.f);

    __syncthreads();

    const int l  = tid & 63;
    const int wv = tid >> 6;
    const int n16 = l & 15;
    const int Q4  = l >> 4;
    const int h   = Q4 & 1;
    const int qh  = Q4 >> 1;

    int Abase[4];
    #pragma unroll
    for (int mf = 0; mf < 4; ++mf) {
        int P  = wv*64 + mf*16 + n16;
        int Pc = P < 483 ? P : 483;
        int pr = Pc >> 2, sb = Pc & 3;
        int py = pr / 11, px = pr - py*11;
        int oy = 2*py + (sb >> 1), ox = 2*px + (sb & 1);
        Abase[mf] = (h*784 + oy*28 + ox) * 16;
    }
    const int Bb0 = qh*1024 + h*512 + n16*16;
    const int Bb1 = Bb0 + 256;

    const char* imgc = (const char*)img_s;
    const char* bsc  = (const char*)bs_s;

    f32x4 acc[4][2];
    #pragma unroll
    for (int mf = 0; mf < 4; ++mf)
        #pragma unroll
        for (int nf = 0; nf < 2; ++nf)
            acc[mf][nf] = (f32x4){0.f, 0.f, 0.f, 0.f};

    #pragma unroll
    for (int t = 0; t < 25; ++t) {
        const int tap0 = 2*t;
        const int tap1 = (2*t + 1 <= 48) ? 2*t + 1 : 48;
        const int o0 = ((tap0/7)*28 + tap0%7) * 16;
        const int o1 = ((tap1/7)*28 + tap1%7) * 16;
        const int offA = qh ? o1 : o0;

        s8v a[4], bf[2];
        #pragma unroll
        for (int mf = 0; mf < 4; ++mf)
            a[mf] = *(const s8v*)(imgc + (Abase[mf] + offA));
        bf[0] = *(const s8v*)(bsc + (Bb0 + t*2048));
        bf[1] = *(const s8v*)(bsc + (Bb1 + t*2048));

        #pragma unroll
        for (int mf = 0; mf < 4; ++mf)
            #pragma unroll
            for (int nf = 0; nf < 2; ++nf)
                acc[mf][nf] = __builtin_amdgcn_mfma_f32_16x16x32_bf16(
                    a[mf], bf[nf], acc[mf][nf], 0, 0, 0);
    }

    #pragma unroll
    for (int nf = 0; nf < 2; ++nf) {
        int co = nf*16 + n16;
        if (co >= 30) continue;
        float A  = g2[co] * rsqrtf(va2[co] + BN_EPS);
        float Bb = (cb2[co] - mu2[co]) * A + be2[co];
        __hip_bfloat16* outp = pool2b + (size_t)b*3840 + co*121;
        #pragma unroll
        for (int mf = 0; mf < 4; ++mf) {
            int pair = wv*16 + mf*4 + Q4;
            if (pair < 121) {
                f32x4 v = acc[mf][nf];
                float m01 = fmaxf(v[0]*A + Bb, v[1]*A + Bb);
                float m23 = fmaxf(v[2]*A + Bb, v[3]*A + Bb);
                outp[pair] = __float2bfloat16(fmaxf(fmaxf(m01, m23), 0.f));
            }
        }
    }
}

// ---------------------------------------------------------------------------
// K3a: fc1 bf16 MFMA GEMM. C[2048,208] = A[2048,3840] * W[208,3840]^T.
// grid 256 = 32 Mtiles(64) x 8 Ksplits(480). block 4 waves; wave = 1 Mfrag x
// 13 Nfrags, fragments direct from global (L2-resident), 15 K-steps of 32.
// ---------------------------------------------------------------------------
__global__ __launch_bounds__(256) void k_fc1(
    const ushort* __restrict__ Ab, const ushort* __restrict__ Wb,
    float* __restrict__ part)
{
    const int tid = threadIdx.x;
    const int bid = blockIdx.x;
    const int ks = bid & 7, mt = bid >> 3;
    const int m0 = mt * 64;
    const int k0 = ks * 480;
    const int wv = tid >> 6, l = tid & 63;
    const int n16 = l & 15, Q4 = l >> 4;

    const ushort* Arow = Ab + (size_t)(m0 + wv*16 + n16) * 3840 + k0 + Q4*8;
    const ushort* Wrow = Wb + (size_t)n16 * 3840 + k0 + Q4*8;

    f32x4 acc[13];
    #pragma unroll
    for (int nf = 0; nf < 13; ++nf) acc[nf] = (f32x4){0.f,0.f,0.f,0.f};

    #pragma unroll 1
    for (int t = 0; t < 15; ++t) {
        s8v a = *(const s8v*)(Arow + t*32);
        s8v bf[13];
        #pragma unroll
        for (int nf = 0; nf < 13; ++nf)
            bf[nf] = *(const s8v*)(Wrow + (size_t)nf*16*3840 + t*32);
        #pragma unroll
        for (int nf = 0; nf < 13; ++nf)
            acc[nf] = __builtin_amdgcn_mfma_f32_16x16x32_bf16(a, bf[nf], acc[nf], 0, 0, 0);
    }

    float* dst = part + ((size_t)ks*2048 + m0 + wv*16 + Q4*4) * 208 + n16;
    #pragma unroll
    for (int nf = 0; nf < 13; ++nf)
        #pragma unroll
        for (int r = 0; r < 4; ++r)
            dst[(size_t)r*208 + nf*16] = acc[nf][r];
}

// ---------------------------------------------------------------------------
// K3b: sum 8 partials + bias + ReLU, fc2 + bias + sigmoid -> float32
// ---------------------------------------------------------------------------
__global__ __launch_bounds__(256) void k_fc2(
    const float* __restrict__ part, const float* __restrict__ fb1,
    const float* __restrict__ W2, const float* __restrict__ fb2,
    float* __restrict__ out)
{
    int b = blockIdx.x * 4 + (threadIdx.x >> 6);
    int l = threadIdx.x & 63;
    float a0 = 0.f, a1 = 0.f;
    #pragma unroll
    for (int j = 0; j < 4; ++j) {
        int n = l + j*64;
        if (n < 200) {
            float v = fb1[n];
            #pragma unroll
            for (int ks = 0; ks < 8; ++ks)
                v += part[((size_t)ks*2048 + b)*208 + n];
            v = fmaxf(v, 0.f);
            a0 += v * W2[n];
            a1 += v * W2[200 + n];
        }
    }
    #pragma unroll
    for (int m = 32; m >= 1; m >>= 1) {
        a0 += __shfl_xor(a0, m);
        a1 += __shfl_xor(a1, m);
    }
    if (l == 0) {
        float z0 = a0 + fb2[0], z1 = a1 + fb2[1];
        out[b*2 + 0] = 1.f / (1.f + expf(-z0));
        out[b*2 + 1] = 1.f / (1.f + expf(-z1));
    }
}

// ---------------------------------------------------------------------------
extern "C" void kernel_launch(void* const* d_in, const int* in_sizes, int n_in,
                              void* d_out, int out_size, void* d_ws, size_t ws_size,
                              hipStream_t stream)
{
    const float* x         = (const float*)d_in[0];
    const float* log_s     = (const float*)d_in[1];
    const float* log_alpha = (const float*)d_in[2];
    const float* log_delta = (const float*)d_in[3];
    const float* log_r     = (const float*)d_in[4];
    const float* conv1_w   = (const float*)d_in[5];
    const float* conv1_b   = (const float*)d_in[6];
    const float* bn1_g     = (const float*)d_in[7];
    const float* bn1_b     = (const float*)d_in[8];
    const float* bn1_m     = (const float*)d_in[9];
    const float* bn1_v     = (const float*)d_in[10];
    const float* conv2_w   = (const float*)d_in[11];
    const float* conv2_b   = (const float*)d_in[12];
    const float* bn2_g     = (const float*)d_in[13];
    const float* bn2_b     = (const float*)d_in[14];
    const float* bn2_m     = (const float*)d_in[15];
    const float* bn2_v     = (const float*)d_in[16];
    const float* fc1_w     = (const float*)d_in[17];
    const float* fc1_b     = (const float*)d_in[18];
    const float* fc2_w     = (const float*)d_in[19];
    const float* fc2_b     = (const float*)d_in[20];

    char* wsb = (char*)d_ws;
    __hip_bfloat16* pool1  = (__hip_bfloat16*)(wsb + POOL1_OFF);
    __hip_bfloat16* wbf    = (__hip_bfloat16*)(wsb + WBF_OFF);
    __hip_bfloat16* wfc1b  = (__hip_bfloat16*)(wsb + WFC1_OFF);
    __hip_bfloat16* w1ex   = (__hip_bfloat16*)(wsb + W1EX_OFF);
    __hip_bfloat16* pool2b = (__hip_bfloat16*)(wsb + POOL2_OFF);
    float* part            = (float*)(wsb + PART_OFF);

    k_wprep_c1<<<68, 256, 0, stream>>>(conv1_w, w1ex);
    k_wprep<<<100, 256, 0, stream>>>(conv2_w, wbf);
    k_wprep_fc1<<<3120, 256, 0, stream>>>(fc1_w, wfc1b);
    k_pcen_conv1<<<2048, 256, 0, stream>>>(x, log_s, log_alpha, log_delta, log_r,
                                           (const ushort*)w1ex, conv1_b,
                                           bn1_g, bn1_b, bn1_m, bn1_v, pool1);
    k_conv2<<<2048, 512, 0, stream>>>((const ushort*)pool1, (const ushort*)wbf,
                                      conv2_b, bn2_g, bn2_b, bn2_m, bn2_v, pool2b);
    k_fc1<<<256, 256, 0, stream>>>((const ushort*)pool2b, (const ushort*)wfc1b, part);
    k_fc2<<<512, 256, 0, stream>>>(part, fc1_b, fc2_w, fc2_b, (float*)d_out);
}